// Round 11
// baseline (886.931 us; speedup 1.0000x reference)
//
#include <hip/hip_runtime.h>
#include <stdint.h>

#define QD 2048
#define KD 1024
#define HID 1024
#define NH 16
#define HD 64
#define CMBD 3072   // QD + KD

typedef float  f32x4   __attribute__((ext_vector_type(4)));
typedef short  short8  __attribute__((ext_vector_type(8)));
typedef short  short4v __attribute__((ext_vector_type(4)));
typedef float  float4v __attribute__((ext_vector_type(4)));

__device__ inline float bf2f(short s) {
  unsigned u = ((unsigned)(unsigned short)s) << 16;
  return __builtin_bit_cast(float, u);
}
__device__ inline short f2bf(float f) {
  unsigned u = __builtin_bit_cast(unsigned, f);
  u = u + 0x7fff + ((u >> 16) & 1);
  return (short)(u >> 16);
}

// ---------------------------------------------------------------- conversions
__global__ void cvt_bf16(const float* __restrict__ s, short* __restrict__ d) {
  size_t i = ((size_t)blockIdx.x * blockDim.x + threadIdx.x) * 4;
  float4v v = *(const float4v*)(s + i);
  short4v o;
  o[0] = f2bf(v[0]); o[1] = f2bf(v[1]); o[2] = f2bf(v[2]); o[3] = f2bf(v[3]);
  *(short4v*)(d + i) = o;
}

__global__ void cvt_concat(const float* __restrict__ s, short* __restrict__ d,
                           int ncols4, int ldd) {
  int i = blockIdx.x * blockDim.x + threadIdx.x;
  int row = i / ncols4;
  int c4  = i - row * ncols4;
  float4v v = *(const float4v*)(s + (size_t)row * (ncols4 * 4) + c4 * 4);
  short4v o;
  o[0] = f2bf(v[0]); o[1] = f2bf(v[1]); o[2] = f2bf(v[2]); o[3] = f2bf(v[3]);
  *(short4v*)(d + (size_t)row * ldd + c4 * 4) = o;
}

// ---------------------------------------------------------------- 256x256 GEMM — A-in-LDS, B-direct-to-reg
// C[M,N] = A[M,K] * W[N,K]^T + bias. bf16 in/out, fp32 accum.
// 8 waves (2M x 4N), per-wave 128x64 C. BK=32.
// A: LDS ring-3 x [256][32] panels (48 KiB static), measured-0-conflict
//    swizzle (granule ^= on gload SOURCE and ds_read addr).
// B: DIRECT global->VGPR fragments (lane reads W[(col..+fr)*K + kq4*8] b128;
//    4 lanes/row = full 64B lines; L2/L3-served), double-buffered bE/bO.
//    Removes B's LDS writes + ds_reads: LDS bytes/K-32 128->80 KB (-37%),
//    barriers/K-32 8->2. Compiler auto-inserts vmcnt for B-use.
// Counted vmcnt for A-stage(t) (issued 2 iters back; per-iter issue = 6):
//   steady WAIT_VM(12); 2nd-last iter 10; last iter 4. Never drains pipe.
#define EPI_NONE 0
#define EPI_GELU 1

typedef const __attribute__((address_space(1))) void gvoid_t;
typedef __attribute__((address_space(3))) void lvoid_t;

#define WAIT_VM(n)  asm volatile("s_waitcnt vmcnt(" #n ")" ::: "memory")

template<int EPI>
__global__ __launch_bounds__(512, 2)
void gemm256(const short* __restrict__ A, size_t lda,
             const short* __restrict__ W,      // [N][K] row-major
             const float* __restrict__ bias,
             short* __restrict__ C, int N, int K) {
  __shared__ short ls[3 * 8192];               // 3 A-slots x 16 KiB = 48 KiB
  const int tid  = threadIdx.x;
  const int lane = tid & 63;
  const int wave = tid >> 6;
  const int wm = wave >> 2, wn = wave & 3;
  const int fr = lane & 15, kq4 = lane >> 4;

  // bijective XCD swizzle (all grids have nwg % 8 == 0)
  const int nwg = gridDim.x * gridDim.y;
  const int lin = blockIdx.y * gridDim.x + blockIdx.x;
  const int cpx = nwg >> 3;
  const int nid = (lin & 7) * cpx + (lin >> 3);
  const int bx = nid % gridDim.x, by = nid / gridDim.x;
  const size_t rowBase = (size_t)by * 256;
  const size_t colBase = (size_t)bx * 256;

  const int NT = K >> 5;                       // 32-wide K tiles (even, >=32)

  f32x4 acc[8][4];
#pragma unroll
  for (int mi = 0; mi < 8; mi++)
#pragma unroll
    for (int ni = 0; ni < 4; ni++) acc[mi][ni] = (f32x4){0.f, 0.f, 0.f, 0.f};

  // A ds_read fragment offsets (shorts)
  const int frsw = (kq4 ^ ((fr >> 1) & 3)) * 8;
  const int aoff = (wm * 128 + fr) * 32 + frsw;          // + m*512

  // A stage pointers (pre-swizzled source granule), advance +=32/tile
  const int grow  = tid >> 2;
  const int slotx = (tid & 3) ^ ((tid >> 3) & 3);
  const short* pA0 = A + (rowBase + grow) * lda + slotx * 8;
  const short* pA1 = pA0 + (size_t)128 * lda;
  short* const dst0 = ls + tid * 8;

  auto STAGE = [&](int slot) {
    short* d = dst0 + slot * 8192;
    __builtin_amdgcn_global_load_lds((gvoid_t*)pA0, (lvoid_t*)d,          16, 0, 0);
    __builtin_amdgcn_global_load_lds((gvoid_t*)pA1, (lvoid_t*)(d + 4096), 16, 0, 0);
    pA0 += 32; pA1 += 32;
  };

  // B per-lane fragment pointer: frag n at +n*16*K, tile t at +t*32
  const short* pb = W + (colBase + wn * 64 + fr) * (size_t)K + kq4 * 8;
  short8 bE[4], bO[4];

  // prologue: A(0); B(0)->bE; A(1)   [issue pattern matches steady state]
  STAGE(0);
#pragma unroll
  for (int n = 0; n < 4; n++) bE[n] = *(const short8*)(pb + n * 16 * (size_t)K);
  pb += 32;
  STAGE(1);

#define GITER(T, bC, bN)                                                      \
  {                                                                           \
    const int t_ = (T);                                                       \
    if (t_ + 1 < NT) {                                                        \
      _Pragma("unroll")                                                       \
      for (int n = 0; n < 4; n++)                                             \
        bN[n] = *(const short8*)(pb + n * 16 * (size_t)K);                    \
      pb += 32;                                                               \
    }                                                                         \
    if (t_ + 2 < NT) STAGE((t_ + 2) % 3);                                     \
    if (t_ + 2 < NT)       { WAIT_VM(12); }                                   \
    else if (t_ + 2 == NT) { WAIT_VM(10); }                                   \
    else                   { WAIT_VM(4); }                                    \
    __builtin_amdgcn_s_barrier();                                             \
    const short* sl_ = ls + (t_ % 3) * 8192;                                  \
    short8 af_[8];                                                            \
    _Pragma("unroll")                                                         \
    for (int m = 0; m < 8; m++) af_[m] = *(const short8*)(sl_ + aoff + m * 512); \
    __builtin_amdgcn_s_setprio(1);                                            \
    _Pragma("unroll")                                                         \
    for (int m = 0; m < 8; m++)                                               \
      _Pragma("unroll")                                                       \
      for (int n = 0; n < 4; n++)                                             \
        acc[m][n] = __builtin_amdgcn_mfma_f32_16x16x32_bf16(af_[m], bC[n], acc[m][n], 0, 0, 0); \
    __builtin_amdgcn_s_setprio(0);                                            \
    __builtin_amdgcn_s_barrier();                                             \
  }

  for (int t = 0; t < NT; t += 2) {
    GITER(t,     bE, bO)
    GITER(t + 1, bO, bE)
  }
#undef GITER

  // epilogue: C/D layout col = lane&15, row = (lane>>4)*4 + reg  (R9 version)
#pragma unroll
  for (int mi = 0; mi < 8; mi++) {
    const size_t row0 = rowBase + wm * 128 + mi * 16 + kq4 * 4;
#pragma unroll
    for (int ni = 0; ni < 4; ni++) {
      const int col = (int)colBase + wn * 64 + ni * 16 + fr;
      const float bv = bias[col];
#pragma unroll
      for (int j = 0; j < 4; j++) {
        float x = acc[mi][ni][j] + bv;
        if (EPI == EPI_GELU) x = 0.5f * x * (1.f + erff(x * 0.70710678118f));
        C[(row0 + j) * (size_t)N + col] = f2bf(x);
      }
    }
  }
}

// ---------------------------------------------------------------- block reduce
__device__ inline float2 block_sum2(float a, float b, float* sc) {
#pragma unroll
  for (int o = 32; o >= 1; o >>= 1) {
    a += __shfl_down(a, o);
    b += __shfl_down(b, o);
  }
  const int lane = threadIdx.x & 63, w = threadIdx.x >> 6;
  const int nw = blockDim.x >> 6;
  if (lane == 0) { sc[w * 2] = a; sc[w * 2 + 1] = b; }
  __syncthreads();
  float ra = 0.f, rb = 0.f;
  for (int i = 0; i < nw; i++) { ra += sc[i * 2]; rb += sc[i * 2 + 1]; }
  __syncthreads();
  return make_float2(ra, rb);
}

// ---------------------------------------------------------------- fused LN(q),LN(k) + 16x16 attention
__global__ __launch_bounds__(256)
void attn_ln(const short* __restrict__ qp, const short* __restrict__ kv,
             const float* __restrict__ lnqw, const float* __restrict__ lnqb,
             const float* __restrict__ lnkw, const float* __restrict__ lnkb,
             short* __restrict__ att) {
  __shared__ float qs[HID];
  __shared__ float ks[NH * 65];
  __shared__ float vs[HID];
  __shared__ float aw[256];
  __shared__ float red[8];
  const int t = threadIdx.x;
  const size_t row = blockIdx.x;

  short4v q4 = *(const short4v*)(qp + row * HID + t * 4);
  short4v k4 = *(const short4v*)(kv + row * 2048 + t * 4);
  short4v v4 = *(const short4v*)(kv + row * 2048 + 1024 + t * 4);
  float qv[4], kvv[4];
  float sq = 0.f, sqq = 0.f, sk = 0.f, skk = 0.f;
#pragma unroll
  for (int i = 0; i < 4; i++) {
    qv[i] = bf2f(q4[i]); sq += qv[i]; sqq += qv[i] * qv[i];
    kvv[i] = bf2f(k4[i]); sk += kvv[i]; skk += kvv[i] * kvv[i];
  }
  float2 rq = block_sum2(sq, sqq, red);
  float mq = rq.x / HID, vq = rq.y / HID - mq * mq;
  float rsq = rsqrtf(vq + 1e-5f);
  float2 rk = block_sum2(sk, skk, red);
  float mk = rk.x / HID, vv = rk.y / HID - mk * mk;
  float rsk = rsqrtf(vv + 1e-5f);
#pragma unroll
  for (int i = 0; i < 4; i++) {
    const int idx = t * 4 + i;
    qs[idx] = (qv[i] - mq) * rsq * lnqw[idx] + lnqb[idx];
    ks[(idx >> 6) * 65 + (idx & 63)] = (kvv[i] - mk) * rsk * lnkw[idx] + lnkb[idx];
    vs[idx] = bf2f(v4[i]);
  }
  __syncthreads();

  const int h = t >> 4, j = t & 15;
  float s = 0.f;
#pragma unroll 8
  for (int d = 0; d < 64; d++) s += qs[h * 64 + d] * ks[j * 65 + d];
  s *= 0.125f;
  float mx = s;
#pragma unroll
  for (int o = 8; o >= 1; o >>= 1) mx = fmaxf(mx, __shfl_xor(mx, o, 16));
  float e = __expf(s - mx);
  float sum = e;
#pragma unroll
  for (int o = 8; o >= 1; o >>= 1) sum += __shfl_xor(sum, o, 16);
  aw[t] = e / sum;
  __syncthreads();

  const int dB = (t & 15) * 4;
  float o0 = 0.f, o1 = 0.f, o2 = 0.f, o3 = 0.f;
#pragma unroll
  for (int jj = 0; jj < 16; jj++) {
    const float w = aw[h * 16 + jj];
    const float* vp = &vs[jj * 64 + dB];
    o0 += w * vp[0]; o1 += w * vp[1]; o2 += w * vp[2]; o3 += w * vp[3];
  }
  short4v o4;
  o4[0] = f2bf(o0); o4[1] = f2bf(o1); o4[2] = f2bf(o2); o4[3] = f2bf(o3);
  *(short4v*)(att + row * HID + h * 64 + dB) = o4;
}

// ---------------------------------------------------------------- gate
__global__ __launch_bounds__(256)
void gate_kernel(const short* __restrict__ hgc,
                 const float* __restrict__ wg2, const float* __restrict__ bg2,
                 const float* __restrict__ wc2, const float* __restrict__ bc2,
                 float* __restrict__ eg) {
  __shared__ float red[8];
  const int t = threadIdx.x;
  const size_t row = blockIdx.x;
  short4v g4 = *(const short4v*)(hgc + row * 2048 + t * 4);
  short4v c4 = *(const short4v*)(hgc + row * 2048 + 1024 + t * 4);
  float sg = 0.f, sc = 0.f;
#pragma unroll
  for (int i = 0; i < 4; i++) {
    sg += bf2f(g4[i]) * wg2[t * 4 + i];
    sc += bf2f(c4[i]) * wc2[t * 4 + i];
  }
  float2 r = block_sum2(sg, sc, red);
  if (t == 0) {
    float g = 1.f / (1.f + __expf(-(r.x + bg2[0])));
    float c = 1.f / (1.f + __expf(-(r.y + bc2[0])));
    eg[row] = g * c;
  }
}

// ---------------------------------------------------------------- final
__global__ __launch_bounds__(256)
void final_kernel(const short* __restrict__ opre, const float* __restrict__ qf,
                  const float* __restrict__ eg,
                  const float* __restrict__ lnow, const float* __restrict__ lnob,
                  float* __restrict__ out) {
  __shared__ float red[8];
  const int t = threadIdx.x;
  const size_t row = blockIdx.x;
  short8 o8 = *(const short8*)(opre + row * QD + t * 8);
  float x[8];
  float s = 0.f, ss = 0.f;
#pragma unroll
  for (int i = 0; i < 8; i++) { x[i] = bf2f(o8[i]); s += x[i]; ss += x[i] * x[i]; }
  float2 r = block_sum2(s, ss, red);
  float m = r.x / QD, v = r.y / QD - m * m;
  float rs = rsqrtf(v + 1e-5f);
  float g = eg[row];
  float4v oa, ob;
#pragma unroll
  for (int i = 0; i < 8; i++) {
    const int c = t * 8 + i;
    float y = (x[i] - m) * rs * lnow[c] + lnob[c];
    float r2 = qf[row * QD + c] + g * y;
    if (i < 4) oa[i] = r2; else ob[i - 4] = r2;
  }
  *(float4v*)(out + row * QD + t * 8) = oa;
  *(float4v*)(out + row * QD + t * 8 + 4) = ob;
}

// ---------------------------------------------------------------- launch
extern "C" void kernel_launch(void* const* d_in, const int* in_sizes, int n_in,
                              void* d_out, int out_size, void* d_ws, size_t ws_size,
                              hipStream_t stream) {
  const float* qf   = (const float*)d_in[0];
  const float* kf   = (const float*)d_in[1];
  const float* Wq   = (const float*)d_in[2];
  const float* bq   = (const float*)d_in[3];
  const float* lnqw = (const float*)d_in[4];
  const float* lnqb = (const float*)d_in[5];
  const float* Wk   = (const float*)d_in[6];
  const float* bk   = (const float*)d_in[7];
  const float* lnkw = (const float*)d_in[8];
  const float* lnkb = (const float*)d_in[9];
  const float* Wvk  = (const float*)d_in[12];
  const float* bvk  = (const float*)d_in[13];
  const float* Wo   = (const float*)d_in[14];
  const float* bo   = (const float*)d_in[15];
  const float* lnow = (const float*)d_in[16];
  const float* lnob = (const float*)d_in[17];
  const float* Wg1  = (const float*)d_in[18];
  const float* bg1  = (const float*)d_in[19];
  const float* Wg2  = (const float*)d_in[20];
  const float* bg2  = (const float*)d_in[21];
  const float* Wc1  = (const float*)d_in[22];
  const float* bc1  = (const float*)d_in[23];
  const float* Wc2  = (const float*)d_in[24];
  const float* bc2  = (const float*)d_in[25];

  const int rows = in_sizes[0] / QD;   // 16384

  char* ws = (char*)d_ws;
  size_t off = 0;
  auto alloc = [&](size_t bytes) -> char* {
    char* p = ws + off;
    off += (bytes + 255) & ~(size_t)255;
    return p;
  };
  short* cmb  = (short*)alloc((size_t)rows * CMBD * 2);
  short* wqb  = (short*)alloc((size_t)HID * QD * 2);
  short* wkv  = (short*)alloc((size_t)2 * HID * KD * 2);
  short* wob  = (short*)alloc((size_t)QD * HID * 2);
  short* wgc  = (short*)alloc((size_t)2 * HID * CMBD * 2);
  short* hgc  = (short*)alloc((size_t)rows * 2048 * 2);
  short* qp   = (short*)alloc((size_t)rows * HID * 2);
  short* kvp  = (short*)alloc((size_t)rows * 2048 * 2);
  float* eg   = (float*)alloc((size_t)rows * 4);
  float* bgc  = (float*)alloc(2048 * 4);
  float* bkv  = (float*)alloc(2048 * 4);
  short* att  = hgc;   // reuse after gate_kernel
  short* opre = cmb;   // reuse after last cmb-reading GEMM

  hipMemcpyAsync(bgc, bg1, HID * 4, hipMemcpyDeviceToDevice, stream);
  hipMemcpyAsync(bgc + HID, bc1, HID * 4, hipMemcpyDeviceToDevice, stream);
  hipMemcpyAsync(bkv, bk, HID * 4, hipMemcpyDeviceToDevice, stream);
  hipMemcpyAsync(bkv + HID, bvk, HID * 4, hipMemcpyDeviceToDevice, stream);

  cvt_concat<<<rows * 2, 256, 0, stream>>>(qf, cmb, QD / 4, CMBD);
  cvt_concat<<<rows, 256, 0, stream>>>(kf, cmb + QD, KD / 4, CMBD);
  cvt_bf16<<<(HID * QD / 4) / 256, 256, 0, stream>>>(Wq, wqb);
  cvt_bf16<<<(HID * KD / 4) / 256, 256, 0, stream>>>(Wk, wkv);
  cvt_bf16<<<(HID * KD / 4) / 256, 256, 0, stream>>>(Wvk, wkv + (size_t)HID * KD);
  cvt_bf16<<<(QD * HID / 4) / 256, 256, 0, stream>>>(Wo, wob);
  cvt_bf16<<<(HID * CMBD / 4) / 256, 256, 0, stream>>>(Wg1, wgc);
  cvt_bf16<<<(HID * CMBD / 4) / 256, 256, 0, stream>>>(Wc1, wgc + (size_t)HID * CMBD);

  const dim3 blk(512);
  const int mt = rows / 256;   // 64

  gemm256<EPI_GELU><<<dim3(2048 / 256, mt), blk, 0, stream>>>(cmb, CMBD, wgc, bgc, hgc, 2048, CMBD);
  gate_kernel<<<rows, 256, 0, stream>>>(hgc, Wg2, bg2, Wc2, bc2, eg);
  gemm256<EPI_NONE><<<dim3(1024 / 256, mt), blk, 0, stream>>>(cmb, CMBD, wqb, bq, qp, 1024, QD);
  gemm256<EPI_NONE><<<dim3(2048 / 256, mt), blk, 0, stream>>>(cmb + QD, CMBD, wkv, bkv, kvp, 2048, KD);
  attn_ln<<<rows, 256, 0, stream>>>(qp, kvp, lnqw, lnqb, lnkw, lnkb, att);
  gemm256<EPI_NONE><<<dim3(2048 / 256, mt), blk, 0, stream>>>(att, HID, wob, bo, opre, 2048, HID);
  final_kernel<<<rows, 256, 0, stream>>>(opre, qf, eg, lnow, lnob, (float*)d_out);
}

// Round 12
// 627.962 us; speedup vs baseline: 1.4124x; 1.4124x over previous
//
#include <hip/hip_runtime.h>
#include <stdint.h>

#define QD 2048
#define KD 1024
#define HID 1024
#define NH 16
#define HD 64
#define CMBD 3072   // QD + KD

typedef float  f32x4   __attribute__((ext_vector_type(4)));
typedef short  short8  __attribute__((ext_vector_type(8)));
typedef short  short4v __attribute__((ext_vector_type(4)));
typedef float  float4v __attribute__((ext_vector_type(4)));

__device__ inline float bf2f(short s) {
  unsigned u = ((unsigned)(unsigned short)s) << 16;
  return __builtin_bit_cast(float, u);
}
__device__ inline short f2bf(float f) {
  unsigned u = __builtin_bit_cast(unsigned, f);
  u = u + 0x7fff + ((u >> 16) & 1);
  return (short)(u >> 16);
}

// ---------------------------------------------------------------- conversions
__global__ void cvt_bf16(const float* __restrict__ s, short* __restrict__ d) {
  size_t i = ((size_t)blockIdx.x * blockDim.x + threadIdx.x) * 4;
  float4v v = *(const float4v*)(s + i);
  short4v o;
  o[0] = f2bf(v[0]); o[1] = f2bf(v[1]); o[2] = f2bf(v[2]); o[3] = f2bf(v[3]);
  *(short4v*)(d + i) = o;
}

__global__ void cvt_concat(const float* __restrict__ s, short* __restrict__ d,
                           int ncols4, int ldd) {
  int i = blockIdx.x * blockDim.x + threadIdx.x;
  int row = i / ncols4;
  int c4  = i - row * ncols4;
  float4v v = *(const float4v*)(s + (size_t)row * (ncols4 * 4) + c4 * 4);
  short4v o;
  o[0] = f2bf(v[0]); o[1] = f2bf(v[1]); o[2] = f2bf(v[2]); o[3] = f2bf(v[3]);
  *(short4v*)(d + (size_t)row * ldd + c4 * 4) = o;
}

// ---------------------------------------------------------------- 256x256 GEMM — 8-phase K-loop (R9, best measured)
// EPI_GATE: no C write; epilogue computes per-row partial of
// sum_col gelu(x+b)*w2[col], shfl-reduces over the 16-lane col group, and
// atomicAdds into egp[half][row] (egp zeroed by memsetAsync each launch).
#define EPI_NONE 0
#define EPI_GELU 1
#define EPI_GATE 2

typedef const __attribute__((address_space(1))) void gvoid_t;
typedef __attribute__((address_space(3))) void lvoid_t;

#define WAIT_VM(n)  asm volatile("s_waitcnt vmcnt(" #n ")" ::: "memory")

#define APAN(b, kp) (((b) * 2 + (kp)) * 8192)
#define BPAN(b, kp) (32768 + ((b) * 2 + (kp)) * 8192)

#define PHASE_MID                                        \
  __builtin_amdgcn_s_barrier();                          \
  asm volatile("s_waitcnt lgkmcnt(0)" ::: "memory");     \
  __builtin_amdgcn_s_setprio(1);

#define PHASE_END                                        \
  __builtin_amdgcn_s_setprio(0);                         \
  __builtin_amdgcn_s_barrier();

template<int EPI>
__global__ __launch_bounds__(512, 2)
void gemm256(const short* __restrict__ A, size_t lda,
             const short* __restrict__ W,      // [N][K] row-major
             const float* __restrict__ bias,
             short* __restrict__ C, int N, int K,
             const float* __restrict__ w2, float* __restrict__ egp, int rowsTot) {
  extern __shared__ short ls[];                // 65536 shorts = 128 KiB
  const int tid  = threadIdx.x;
  const int lane = tid & 63;
  const int wave = tid >> 6;
  const int wm = wave >> 2, wn = wave & 3;
  const int fr = lane & 15, kq4 = lane >> 4;

  // bijective XCD swizzle (all grids have nwg % 8 == 0)
  const int nwg = gridDim.x * gridDim.y;
  const int lin = blockIdx.y * gridDim.x + blockIdx.x;
  const int cpx = nwg >> 3;
  const int nid = (lin & 7) * cpx + (lin >> 3);
  const int bx = nid % gridDim.x, by = nid / gridDim.x;
  const size_t rowBase = (size_t)by * 256;
  const size_t colBase = (size_t)bx * 256;

  const int NTT = K >> 6;                      // K-64 tiles (even)

  f32x4 acc[8][4];
#pragma unroll
  for (int mi = 0; mi < 8; mi++)
#pragma unroll
    for (int ni = 0; ni < 4; ni++) acc[mi][ni] = (f32x4){0.f, 0.f, 0.f, 0.f};

  const int frsw = (kq4 ^ ((fr >> 1) & 3)) * 8;

  const int grow  = tid >> 2;
  const int slotx = (tid & 3) ^ ((tid >> 3) & 3);
  const short* gAlo = A + (rowBase + grow) * lda + slotx * 8;
  const short* gAhi = gAlo + (size_t)128 * lda;
  const short* gBlo = W + (colBase + grow) * (size_t)K + slotx * 8;
  const short* gBhi = gBlo + (size_t)128 * K;
  short* const sdst = ls + tid * 8;

  auto STG_A = [&](int panOff, int kcol) {
    __builtin_amdgcn_global_load_lds((gvoid_t*)(gAlo + kcol), (lvoid_t*)(sdst + panOff),        16, 0, 0);
    __builtin_amdgcn_global_load_lds((gvoid_t*)(gAhi + kcol), (lvoid_t*)(sdst + panOff + 4096), 16, 0, 0);
  };
  auto STG_B = [&](int panOff, int kcol) {
    __builtin_amdgcn_global_load_lds((gvoid_t*)(gBlo + kcol), (lvoid_t*)(sdst + panOff),        16, 0, 0);
    __builtin_amdgcn_global_load_lds((gvoid_t*)(gBhi + kcol), (lvoid_t*)(sdst + panOff + 4096), 16, 0, 0);
  };

  STG_A(APAN(0, 0), 0);  STG_A(APAN(0, 1), 32);
  STG_B(BPAN(0, 0), 0);  STG_B(BPAN(0, 1), 32);
  STG_B(BPAN(1, 0), 64); STG_B(BPAN(1, 1), 96);
  WAIT_VM(4);
  __builtin_amdgcn_s_barrier();

  short8 fa0[8], fa1[8], fb0[4], fb1[4];

  for (int t = 0; t < NTT; t += 2) {
    const bool more = (t + 2 < NTT);
    const int kA1 = (t + 1) * 64;
    const int kE2 = (t + 2) * 64;
    const int kO3 = (t + 3) * 64;

    // even half: buf0 (tile t)
#pragma unroll
    for (int m = 0; m < 4; m++) {
      const int r = (wm * 128 + m * 16 + fr) * 32 + frsw;
      fa0[m * 2 + 0] = *(const short8*)(ls + APAN(0, 0) + r);
      fa0[m * 2 + 1] = *(const short8*)(ls + APAN(0, 1) + r);
    }
#pragma unroll
    for (int n = 0; n < 2; n++) {
      const int r = (wn * 64 + n * 16 + fr) * 32 + frsw;
      fb0[n * 2 + 0] = *(const short8*)(ls + BPAN(0, 0) + r);
      fb0[n * 2 + 1] = *(const short8*)(ls + BPAN(0, 1) + r);
    }
    STG_A(APAN(1, 0), kA1);
    PHASE_MID
#pragma unroll
    for (int m = 0; m < 4; m++)
#pragma unroll
      for (int n = 0; n < 2; n++) {
        acc[m][n] = __builtin_amdgcn_mfma_f32_16x16x32_bf16(fa0[m*2+0], fb0[n*2+0], acc[m][n], 0, 0, 0);
        acc[m][n] = __builtin_amdgcn_mfma_f32_16x16x32_bf16(fa0[m*2+1], fb0[n*2+1], acc[m][n], 0, 0, 0);
      }
    PHASE_END

#pragma unroll
    for (int n = 0; n < 2; n++) {
      const int r = (wn * 64 + (n + 2) * 16 + fr) * 32 + frsw;
      fb1[n * 2 + 0] = *(const short8*)(ls + BPAN(0, 0) + r);
      fb1[n * 2 + 1] = *(const short8*)(ls + BPAN(0, 1) + r);
    }
    STG_A(APAN(1, 1), kA1 + 32);
    PHASE_MID
#pragma unroll
    for (int m = 0; m < 4; m++)
#pragma unroll
      for (int n = 0; n < 2; n++) {
        acc[m][n+2] = __builtin_amdgcn_mfma_f32_16x16x32_bf16(fa0[m*2+0], fb1[n*2+0], acc[m][n+2], 0, 0, 0);
        acc[m][n+2] = __builtin_amdgcn_mfma_f32_16x16x32_bf16(fa0[m*2+1], fb1[n*2+1], acc[m][n+2], 0, 0, 0);
      }
    PHASE_END

#pragma unroll
    for (int m = 0; m < 4; m++) {
      const int r = (wm * 128 + (m + 4) * 16 + fr) * 32 + frsw;
      fa1[m * 2 + 0] = *(const short8*)(ls + APAN(0, 0) + r);
      fa1[m * 2 + 1] = *(const short8*)(ls + APAN(0, 1) + r);
    }
    if (more) STG_B(BPAN(0, 0), kE2);
    PHASE_MID
#pragma unroll
    for (int m = 0; m < 4; m++)
#pragma unroll
      for (int n = 0; n < 2; n++) {
        acc[m+4][n] = __builtin_amdgcn_mfma_f32_16x16x32_bf16(fa1[m*2+0], fb0[n*2+0], acc[m+4][n], 0, 0, 0);
        acc[m+4][n] = __builtin_amdgcn_mfma_f32_16x16x32_bf16(fa1[m*2+1], fb0[n*2+1], acc[m+4][n], 0, 0, 0);
      }
    PHASE_END

    if (more) STG_B(BPAN(0, 1), kE2 + 32);
    PHASE_MID
#pragma unroll
    for (int m = 0; m < 4; m++)
#pragma unroll
      for (int n = 0; n < 2; n++) {
        acc[m+4][n+2] = __builtin_amdgcn_mfma_f32_16x16x32_bf16(fa1[m*2+0], fb1[n*2+0], acc[m+4][n+2], 0, 0, 0);
        acc[m+4][n+2] = __builtin_amdgcn_mfma_f32_16x16x32_bf16(fa1[m*2+1], fb1[n*2+1], acc[m+4][n+2], 0, 0, 0);
      }
    __builtin_amdgcn_s_setprio(0);
    if (more) { WAIT_VM(4); } else { WAIT_VM(0); }
    __builtin_amdgcn_s_barrier();

    // odd half: buf1 (tile t+1)
#pragma unroll
    for (int m = 0; m < 4; m++) {
      const int r = (wm * 128 + m * 16 + fr) * 32 + frsw;
      fa0[m * 2 + 0] = *(const short8*)(ls + APAN(1, 0) + r);
      fa0[m * 2 + 1] = *(const short8*)(ls + APAN(1, 1) + r);
    }
#pragma unroll
    for (int n = 0; n < 2; n++) {
      const int r = (wn * 64 + n * 16 + fr) * 32 + frsw;
      fb0[n * 2 + 0] = *(const short8*)(ls + BPAN(1, 0) + r);
      fb0[n * 2 + 1] = *(const short8*)(ls + BPAN(1, 1) + r);
    }
    if (more) STG_A(APAN(0, 0), kE2);
    PHASE_MID
#pragma unroll
    for (int m = 0; m < 4; m++)
#pragma unroll
      for (int n = 0; n < 2; n++) {
        acc[m][n] = __builtin_amdgcn_mfma_f32_16x16x32_bf16(fa0[m*2+0], fb0[n*2+0], acc[m][n], 0, 0, 0);
        acc[m][n] = __builtin_amdgcn_mfma_f32_16x16x32_bf16(fa0[m*2+1], fb0[n*2+1], acc[m][n], 0, 0, 0);
      }
    PHASE_END

#pragma unroll
    for (int n = 0; n < 2; n++) {
      const int r = (wn * 64 + (n + 2) * 16 + fr) * 32 + frsw;
      fb1[n * 2 + 0] = *(const short8*)(ls + BPAN(1, 0) + r);
      fb1[n * 2 + 1] = *(const short8*)(ls + BPAN(1, 1) + r);
    }
    if (more) STG_A(APAN(0, 1), kE2 + 32);
    PHASE_MID
#pragma unroll
    for (int m = 0; m < 4; m++)
#pragma unroll
      for (int n = 0; n < 2; n++) {
        acc[m][n+2] = __builtin_amdgcn_mfma_f32_16x16x32_bf16(fa0[m*2+0], fb1[n*2+0], acc[m][n+2], 0, 0, 0);
        acc[m][n+2] = __builtin_amdgcn_mfma_f32_16x16x32_bf16(fa0[m*2+1], fb1[n*2+1], acc[m][n+2], 0, 0, 0);
      }
    PHASE_END

#pragma unroll
    for (int m = 0; m < 4; m++) {
      const int r = (wm * 128 + (m + 4) * 16 + fr) * 32 + frsw;
      fa1[m * 2 + 0] = *(const short8*)(ls + APAN(1, 0) + r);
      fa1[m * 2 + 1] = *(const short8*)(ls + APAN(1, 1) + r);
    }
    if (more) STG_B(BPAN(1, 0), kO3);
    PHASE_MID
#pragma unroll
    for (int m = 0; m < 4; m++)
#pragma unroll
      for (int n = 0; n < 2; n++) {
        acc[m+4][n] = __builtin_amdgcn_mfma_f32_16x16x32_bf16(fa1[m*2+0], fb0[n*2+0], acc[m+4][n], 0, 0, 0);
        acc[m+4][n] = __builtin_amdgcn_mfma_f32_16x16x32_bf16(fa1[m*2+1], fb0[n*2+1], acc[m+4][n], 0, 0, 0);
      }
    PHASE_END

    if (more) STG_B(BPAN(1, 1), kO3 + 32);
    PHASE_MID
#pragma unroll
    for (int m = 0; m < 4; m++)
#pragma unroll
      for (int n = 0; n < 2; n++) {
        acc[m+4][n+2] = __builtin_amdgcn_mfma_f32_16x16x32_bf16(fa1[m*2+0], fb1[n*2+0], acc[m+4][n+2], 0, 0, 0);
        acc[m+4][n+2] = __builtin_amdgcn_mfma_f32_16x16x32_bf16(fa1[m*2+1], fb1[n*2+1], acc[m+4][n+2], 0, 0, 0);
      }
    __builtin_amdgcn_s_setprio(0);
    if (more) { WAIT_VM(4); }
    __builtin_amdgcn_s_barrier();
  }

  if (EPI == EPI_GATE) {
    // fused gate: per-row partial of sum_col gelu(x+b)*w2[col]
    float w2v[4], bvv[4];
#pragma unroll
    for (int ni = 0; ni < 4; ni++) {
      const int c = (int)colBase + wn * 64 + ni * 16 + fr;
      w2v[ni] = w2[c]; bvv[ni] = bias[c];
    }
    const int half = (colBase >= 1024) ? 1 : 0;
#pragma unroll
    for (int mi = 0; mi < 8; mi++) {
      float sj[4] = {0.f, 0.f, 0.f, 0.f};
#pragma unroll
      for (int ni = 0; ni < 4; ni++)
#pragma unroll
        for (int j = 0; j < 4; j++) {
          float x = acc[mi][ni][j] + bvv[ni];
          float g = 0.5f * x * (1.f + erff(x * 0.70710678118f));
          sj[j] += g * w2v[ni];
        }
#pragma unroll
      for (int j = 0; j < 4; j++) {
#pragma unroll
        for (int o = 8; o >= 1; o >>= 1) sj[j] += __shfl_xor(sj[j], o);
        if (fr == 0) {
          const int row = (int)rowBase + wm * 128 + mi * 16 + kq4 * 4 + j;
          atomicAdd(egp + half * rowsTot + row, sj[j]);
        }
      }
    }
  } else {
    // epilogue: C/D layout col = lane&15, row = (lane>>4)*4 + reg
#pragma unroll
    for (int mi = 0; mi < 8; mi++) {
      const size_t row0 = rowBase + wm * 128 + mi * 16 + kq4 * 4;
#pragma unroll
      for (int ni = 0; ni < 4; ni++) {
        const int col = (int)colBase + wn * 64 + ni * 16 + fr;
        const float bv = bias[col];
#pragma unroll
        for (int j = 0; j < 4; j++) {
          float x = acc[mi][ni][j] + bv;
          if (EPI == EPI_GELU) x = 0.5f * x * (1.f + erff(x * 0.70710678118f));
          C[(row0 + j) * (size_t)N + col] = f2bf(x);
        }
      }
    }
  }
}

// ---------------------------------------------------------------- block reduce (4-wide)
__device__ inline float4 block_sum4(float a, float b, float c, float d, float* sc) {
#pragma unroll
  for (int o = 32; o >= 1; o >>= 1) {
    a += __shfl_down(a, o); b += __shfl_down(b, o);
    c += __shfl_down(c, o); d += __shfl_down(d, o);
  }
  const int lane = threadIdx.x & 63, w = threadIdx.x >> 6;
  const int nw = blockDim.x >> 6;
  if (lane == 0) { sc[w*4] = a; sc[w*4+1] = b; sc[w*4+2] = c; sc[w*4+3] = d; }
  __syncthreads();
  float ra = 0.f, rb = 0.f, rc = 0.f, rd = 0.f;
  for (int i = 0; i < nw; i++) { ra += sc[i*4]; rb += sc[i*4+1]; rc += sc[i*4+2]; rd += sc[i*4+3]; }
  __syncthreads();
  return make_float4(ra, rb, rc, rd);
}
__device__ inline float2 block_sum2(float a, float b, float* sc) {
#pragma unroll
  for (int o = 32; o >= 1; o >>= 1) { a += __shfl_down(a, o); b += __shfl_down(b, o); }
  const int lane = threadIdx.x & 63, w = threadIdx.x >> 6;
  const int nw = blockDim.x >> 6;
  if (lane == 0) { sc[w*2] = a; sc[w*2+1] = b; }
  __syncthreads();
  float ra = 0.f, rb = 0.f;
  for (int i = 0; i < nw; i++) { ra += sc[i*2]; rb += sc[i*2+1]; }
  __syncthreads();
  return make_float2(ra, rb);
}

// ---------------------------------------------------------------- fused LN(q),LN(k) + 16x16 attention
__global__ __launch_bounds__(256)
void attn_ln(const short* __restrict__ qp, const short* __restrict__ kv,
             const float* __restrict__ lnqw, const float* __restrict__ lnqb,
             const float* __restrict__ lnkw, const float* __restrict__ lnkb,
             short* __restrict__ att) {
  __shared__ float qs[HID];
  __shared__ float ks[NH * 65];
  __shared__ float vs[HID];
  __shared__ float aw[256];
  __shared__ float red[16];
  const int t = threadIdx.x;
  const size_t row = blockIdx.x;

  short4v q4 = *(const short4v*)(qp + row * HID + t * 4);
  short4v k4 = *(const short4v*)(kv + row * 2048 + t * 4);
  short4v v4 = *(const short4v*)(kv + row * 2048 + 1024 + t * 4);
  float qv[4], kvv[4];
  float sq = 0.f, sqq = 0.f, sk = 0.f, skk = 0.f;
#pragma unroll
  for (int i = 0; i < 4; i++) {
    qv[i] = bf2f(q4[i]); sq += qv[i]; sqq += qv[i] * qv[i];
    kvv[i] = bf2f(k4[i]); sk += kvv[i]; skk += kvv[i] * kvv[i];
  }
  float4 r4 = block_sum4(sq, sqq, sk, skk, red);
  float mq = r4.x / HID, vq = r4.y / HID - mq * mq;
  float rsq = rsqrtf(vq + 1e-5f);
  float mk = r4.z / HID, vv = r4.w / HID - mk * mk;
  float rsk = rsqrtf(vv + 1e-5f);
#pragma unroll
  for (int i = 0; i < 4; i++) {
    const int idx = t * 4 + i;
    qs[idx] = (qv[i] - mq) * rsq * lnqw[idx] + lnqb[idx];
    ks[(idx >> 6) * 65 + (idx & 63)] = (kvv[i] - mk) * rsk * lnkw[idx] + lnkb[idx];
    vs[idx] = bf2f(v4[i]);
  }
  __syncthreads();

  const int h = t >> 4, j = t & 15;
  float s = 0.f;
#pragma unroll 8
  for (int d = 0; d < 64; d++) s += qs[h * 64 + d] * ks[j * 65 + d];
  s *= 0.125f;
  float mx = s;
#pragma unroll
  for (int o = 8; o >= 1; o >>= 1) mx = fmaxf(mx, __shfl_xor(mx, o, 16));
  float e = __expf(s - mx);
  float sum = e;
#pragma unroll
  for (int o = 8; o >= 1; o >>= 1) sum += __shfl_xor(sum, o, 16);
  aw[t] = e / sum;
  __syncthreads();

  const int dB = (t & 15) * 4;
  float o0 = 0.f, o1 = 0.f, o2 = 0.f, o3 = 0.f;
#pragma unroll
  for (int jj = 0; jj < 16; jj++) {
    const float w = aw[h * 16 + jj];
    const float* vp = &vs[jj * 64 + dB];
    o0 += w * vp[0]; o1 += w * vp[1]; o2 += w * vp[2]; o3 += w * vp[3];
  }
  short4v o4;
  o4[0] = f2bf(o0); o4[1] = f2bf(o1); o4[2] = f2bf(o2); o4[3] = f2bf(o3);
  *(short4v*)(att + row * HID + h * 64 + dB) = o4;
}

// ---------------------------------------------------------------- final: out = qf + eg * LN_o(opre), eg from egp
__global__ __launch_bounds__(256)
void final_kernel(const short* __restrict__ opre, const float* __restrict__ qf,
                  const float* __restrict__ egp, int rowsTot,
                  const float* __restrict__ bg2, const float* __restrict__ bc2,
                  const float* __restrict__ lnow, const float* __restrict__ lnob,
                  float* __restrict__ out) {
  __shared__ float red[8];
  const int t = threadIdx.x;
  const size_t row = blockIdx.x;
  short8 o8 = *(const short8*)(opre + row * QD + t * 8);
  float x[8];
  float s = 0.f, ss = 0.f;
#pragma unroll
  for (int i = 0; i < 8; i++) { x[i] = bf2f(o8[i]); s += x[i]; ss += x[i] * x[i]; }
  float2 r = block_sum2(s, ss, red);
  float m = r.x / QD, v = r.y / QD - m * m;
  float rs = rsqrtf(v + 1e-5f);
  float gg = 1.f / (1.f + __expf(-(egp[row] + bg2[0])));
  float gc = 1.f / (1.f + __expf(-(egp[rowsTot + row] + bc2[0])));
  float g = gg * gc;
  float4v oa, ob;
#pragma unroll
  for (int i = 0; i < 8; i++) {
    const int c = t * 8 + i;
    float y = (x[i] - m) * rs * lnow[c] + lnob[c];
    float r2 = qf[row * QD + c] + g * y;
    if (i < 4) oa[i] = r2; else ob[i - 4] = r2;
  }
  *(float4v*)(out + row * QD + t * 8) = oa;
  *(float4v*)(out + row * QD + t * 8 + 4) = ob;
}

// ---------------------------------------------------------------- launch
extern "C" void kernel_launch(void* const* d_in, const int* in_sizes, int n_in,
                              void* d_out, int out_size, void* d_ws, size_t ws_size,
                              hipStream_t stream) {
  const float* qf   = (const float*)d_in[0];
  const float* kf   = (const float*)d_in[1];
  const float* Wq   = (const float*)d_in[2];
  const float* bq   = (const float*)d_in[3];
  const float* lnqw = (const float*)d_in[4];
  const float* lnqb = (const float*)d_in[5];
  const float* Wk   = (const float*)d_in[6];
  const float* bk   = (const float*)d_in[7];
  const float* lnkw = (const float*)d_in[8];
  const float* lnkb = (const float*)d_in[9];
  const float* Wvk  = (const float*)d_in[12];
  const float* bvk  = (const float*)d_in[13];
  const float* Wo   = (const float*)d_in[14];
  const float* bo   = (const float*)d_in[15];
  const float* lnow = (const float*)d_in[16];
  const float* lnob = (const float*)d_in[17];
  const float* Wg1  = (const float*)d_in[18];
  const float* bg1  = (const float*)d_in[19];
  const float* Wg2  = (const float*)d_in[20];
  const float* bg2  = (const float*)d_in[21];
  const float* Wc1  = (const float*)d_in[22];
  const float* bc1  = (const float*)d_in[23];
  const float* Wc2  = (const float*)d_in[24];
  const float* bc2  = (const float*)d_in[25];

  const int rows = in_sizes[0] / QD;   // 16384

  char* ws = (char*)d_ws;
  size_t off = 0;
  auto alloc = [&](size_t bytes) -> char* {
    char* p = ws + off;
    off += (bytes + 255) & ~(size_t)255;
    return p;
  };
  short* cmb  = (short*)alloc((size_t)rows * CMBD * 2);
  short* wqb  = (short*)alloc((size_t)HID * QD * 2);
  short* wkv  = (short*)alloc((size_t)2 * HID * KD * 2);
  short* wob  = (short*)alloc((size_t)QD * HID * 2);
  short* wgc  = (short*)alloc((size_t)2 * HID * CMBD * 2);
  short* hgc  = (short*)alloc((size_t)rows * 2048 * 2);   // scratch for att
  short* qp   = (short*)alloc((size_t)rows * HID * 2);
  short* kvp  = (short*)alloc((size_t)rows * 2048 * 2);
  float* egp  = (float*)alloc((size_t)2 * rows * 4);      // gate partials [2][rows]
  float* bgc  = (float*)alloc(2048 * 4);
  float* bkv  = (float*)alloc(2048 * 4);
  float* w2gc = (float*)alloc(2048 * 4);                  // Wg2 ‖ Wc2
  short* att  = hgc;
  short* opre = cmb;   // reuse after last cmb-reading GEMM

  hipMemcpyAsync(bgc, bg1, HID * 4, hipMemcpyDeviceToDevice, stream);
  hipMemcpyAsync(bgc + HID, bc1, HID * 4, hipMemcpyDeviceToDevice, stream);
  hipMemcpyAsync(bkv, bk, HID * 4, hipMemcpyDeviceToDevice, stream);
  hipMemcpyAsync(bkv + HID, bvk, HID * 4, hipMemcpyDeviceToDevice, stream);
  hipMemcpyAsync(w2gc, Wg2, HID * 4, hipMemcpyDeviceToDevice, stream);
  hipMemcpyAsync(w2gc + HID, Wc2, HID * 4, hipMemcpyDeviceToDevice, stream);
  hipMemsetAsync(egp, 0, (size_t)2 * rows * 4, stream);

  cvt_concat<<<rows * 2, 256, 0, stream>>>(qf, cmb, QD / 4, CMBD);
  cvt_concat<<<rows, 256, 0, stream>>>(kf, cmb + QD, KD / 4, CMBD);
  cvt_bf16<<<(HID * QD / 4) / 256, 256, 0, stream>>>(Wq, wqb);
  cvt_bf16<<<(HID * KD / 4) / 256, 256, 0, stream>>>(Wk, wkv);
  cvt_bf16<<<(HID * KD / 4) / 256, 256, 0, stream>>>(Wvk, wkv + (size_t)HID * KD);
  cvt_bf16<<<(QD * HID / 4) / 256, 256, 0, stream>>>(Wo, wob);
  cvt_bf16<<<(HID * CMBD / 4) / 256, 256, 0, stream>>>(Wg1, wgc);
  cvt_bf16<<<(HID * CMBD / 4) / 256, 256, 0, stream>>>(Wc1, wgc + (size_t)HID * CMBD);

  hipFuncSetAttribute((const void*)gemm256<EPI_GATE>,
                      hipFuncAttributeMaxDynamicSharedMemorySize, 131072);
  hipFuncSetAttribute((const void*)gemm256<EPI_NONE>,
                      hipFuncAttributeMaxDynamicSharedMemorySize, 131072);

  const dim3 blk(512);
  const int mt = rows / 256;   // 64
  const size_t lds = 131072;

  // fused gate GEMM: no C write; accumulates egp
  gemm256<EPI_GATE><<<dim3(2048 / 256, mt), blk, lds, stream>>>(cmb, CMBD, wgc, bgc, hgc, 2048, CMBD, w2gc, egp, rows);
  gemm256<EPI_NONE><<<dim3(1024 / 256, mt), blk, lds, stream>>>(cmb, CMBD, wqb, bq, qp, 1024, QD, nullptr, nullptr, 0);
  gemm256<EPI_NONE><<<dim3(2048 / 256, mt), blk, lds, stream>>>(cmb + QD, CMBD, wkv, bkv, kvp, 2048, KD, nullptr, nullptr, 0);
  attn_ln<<<rows, 256, 0, stream>>>(qp, kvp, lnqw, lnqb, lnkw, lnkb, att);
  gemm256<EPI_NONE><<<dim3(2048 / 256, mt), blk, lds, stream>>>(att, HID, wob, bo, opre, 2048, HID, nullptr, nullptr, 0);
  final_kernel<<<rows, 256, 0, stream>>>(opre, qf, egp, rows, bg2, bc2, lnow, lnob, (float*)d_out);
}